// Round 1
// baseline (612.602 us; speedup 1.0000x reference)
//
#include <hip/hip_runtime.h>

#define BB 4
#define CC 32
#define HH 128
#define WW 256
#define CR 85
#define EPSF 1e-5f

// Output offsets (elements) in concatenated d_out:
// out0 [B,C,H,W] @ 0; out1 @ 4194304; out2 [B,H,W,W] @ 8388608; out3 @ 41943040
#define O1_OFF 4194304
#define O2_OFF 8388608
#define O3_OFF 41943040
#define COST1_OFF (BB*HH*WW*WW)   // 33554432

__global__ __launch_bounds__(256, 2)
void pab_fused(const float* __restrict__ x_left, const float* __restrict__ x_right,
               const float* __restrict__ cost,
               const float* __restrict__ q_w, const float* __restrict__ q_b,
               const float* __restrict__ q_gamma, const float* __restrict__ q_beta,
               const float* __restrict__ q_mean, const float* __restrict__ q_var,
               const float* __restrict__ k_w, const float* __restrict__ k_b,
               const float* __restrict__ k_gamma, const float* __restrict__ k_beta,
               const float* __restrict__ k_mean, const float* __restrict__ k_var,
               float* __restrict__ out)
{
    __shared__ float qwt[CC][CC];   // [c][o], BN-folded, transposed for broadcast float4 reads
    __shared__ float kwt[CC][CC];
    __shared__ float qbf[CC], kbf[CC], qsc[CC], ksc[CC];
    __shared__ float Qls[WW][CC];   // Q_l rows (32 floats = 128B, 16B aligned)
    __shared__ float Qrs[WW][CC];   // Q_r rows

    const int t   = threadIdx.x;    // owns column j = t
    const int bid = blockIdx.x;     // b*H + h
    const int b   = bid >> 7;
    const int h   = bid & 127;

    // ---- Phase 0: fold BN into weights/bias (redundant per block, tiny) ----
    if (t < CC) {
        float qs = q_gamma[t] * rsqrtf(q_var[t] + EPSF);
        float ks = k_gamma[t] * rsqrtf(k_var[t] + EPSF);
        qsc[t] = qs; ksc[t] = ks;
        qbf[t] = q_b[t] * qs + q_beta[t] - q_mean[t] * qs;
        kbf[t] = k_b[t] * ks + k_beta[t] - k_mean[t] * ks;
    }
    __syncthreads();
    for (int r = t; r < CC * CC; r += 256) {
        int o = r >> 5, c = r & 31;          // w[o][c] at flat r
        qwt[c][o] = q_w[r] * qsc[o];
        kwt[c][o] = k_w[r] * ksc[o];
    }
    __syncthreads();

    // ---- Phase 1: projections + fused 2*x outputs ----
    float ql[CC], qr[CC], kl[CC], kr[CC];
    #pragma unroll
    for (int o = 0; o < CC; ++o) {
        float qb0 = qbf[o], kb0 = kbf[o];
        ql[o] = qb0; qr[o] = qb0; kl[o] = kb0; kr[o] = kb0;
    }

    const int xbase = (b * CC * HH + h) * WW + t;   // c stride = H*W
    #pragma unroll 4
    for (int c = 0; c < CC; ++c) {
        int idx = xbase + c * (HH * WW);
        float xl = x_left[idx];
        float xr = x_right[idx];
        out[idx]          = 2.0f * xl;   // out0 = 2*x_left  (x read exactly once)
        out[O1_OFF + idx] = 2.0f * xr;   // out1 = 2*x_right
        #pragma unroll
        for (int o = 0; o < CC; ++o) {
            float qw = qwt[c][o];
            float kw = kwt[c][o];
            ql[o] += xl * qw;   // Q from x_left
            kl[o] += xl * kw;   // K from x_left
            qr[o] += xr * qw;   // Q from x_right
            kr[o] += xr * kw;   // K from x_right
        }
    }
    #pragma unroll
    for (int o = 0; o < CC; o += 4) {
        *(float4*)&Qls[t][o] = make_float4(ql[o], ql[o+1], ql[o+2], ql[o+3]);
        *(float4*)&Qrs[t][o] = make_float4(qr[o], qr[o+1], qr[o+2], qr[o+3]);
    }
    __syncthreads();

    // ---- Phase 2: stream cost rows, add banded scores ----
    // thread t = column j; row i: r2l band 0<=i-j<CR uses dot(Q_l[i], K_r[j]);
    //                             l2r band 0<=j-i<CR uses dot(Q_r[i], K_l[j]).
    const int rowbase = bid * (WW * WW) + t;
    const float* __restrict__ c0 = cost + rowbase;             // cost[0,b,h,:,j]
    const float* __restrict__ c1 = cost + COST1_OFF + rowbase; // cost[1,b,h,:,j]
    float* __restrict__ o2 = out + O2_OFF + rowbase;
    float* __restrict__ o3 = out + O3_OFF + rowbase;

    #pragma unroll 2
    for (int i = 0; i < WW; ++i) {
        float v0 = c0[i * WW];
        float v1 = c1[i * WW];
        int d = i - t;
        if (d >= 0 && d < CR) {
            float s = 0.f;
            #pragma unroll
            for (int o = 0; o < CC; o += 4) {
                float4 q = *(const float4*)&Qls[i][o];   // uniform addr -> broadcast
                s += q.x * kr[o] + q.y * kr[o+1] + q.z * kr[o+2] + q.w * kr[o+3];
            }
            v0 += s * (1.0f / 32.0f);
        }
        if (d <= 0 && d > -CR) {
            float s = 0.f;
            #pragma unroll
            for (int o = 0; o < CC; o += 4) {
                float4 q = *(const float4*)&Qrs[i][o];
                s += q.x * kl[o] + q.y * kl[o+1] + q.z * kl[o+2] + q.w * kl[o+3];
            }
            v1 += s * (1.0f / 32.0f);
        }
        o2[i * WW] = v0;
        o3[i * WW] = v1;
    }
}

extern "C" void kernel_launch(void* const* d_in, const int* in_sizes, int n_in,
                              void* d_out, int out_size, void* d_ws, size_t ws_size,
                              hipStream_t stream) {
    const float* x_left  = (const float*)d_in[0];
    const float* x_right = (const float*)d_in[1];
    const float* cost    = (const float*)d_in[2];
    const float* q_w     = (const float*)d_in[3];
    const float* q_b     = (const float*)d_in[4];
    const float* q_gamma = (const float*)d_in[5];
    const float* q_beta  = (const float*)d_in[6];
    const float* q_mean  = (const float*)d_in[7];
    const float* q_var   = (const float*)d_in[8];
    const float* k_w     = (const float*)d_in[9];
    const float* k_b     = (const float*)d_in[10];
    const float* k_gamma = (const float*)d_in[11];
    const float* k_beta  = (const float*)d_in[12];
    const float* k_mean  = (const float*)d_in[13];
    const float* k_var   = (const float*)d_in[14];
    float* out = (float*)d_out;

    pab_fused<<<dim3(BB * HH), dim3(256), 0, stream>>>(
        x_left, x_right, cost,
        q_w, q_b, q_gamma, q_beta, q_mean, q_var,
        k_w, k_b, k_gamma, k_beta, k_mean, k_var,
        out);
}

// Round 2
// 558.861 us; speedup vs baseline: 1.0962x; 1.0962x over previous
//
#include <hip/hip_runtime.h>

#define BB 4
#define CC 32
#define HH 128
#define WW 256
#define CR 85
#define EPSF 1e-5f

// Output offsets (elements): out0 @0, out1 @4194304, out2 @8388608, out3 @41943040
#define O1_OFF 4194304
#define O2_OFF 8388608
#define COST1 33554432   // elements per direction of cost / out2-3

typedef __attribute__((ext_vector_type(8))) short bf16x8;
typedef __attribute__((ext_vector_type(4))) float f32x4;

// ws layout (ushort bf16): Q[side][512][256][32] then K[side][512][256][32]
// side 0 = from x_left (Q_l, K_l), side 1 = from x_right (Q_r, K_r)
#define ARR (512 * 256 * 32)
#define WS_Q(side) ((side) * ARR)
#define WS_K(side) (2 * ARR + (side) * ARR)
#define WS_NEEDED (4ull * ARR * 2ull)   // bytes

static __device__ __forceinline__ unsigned short f2bf(float f) {
    unsigned u = __float_as_uint(f);
    unsigned r = (u + 0x7FFFu + ((u >> 16) & 1u)) >> 16;   // RNE
    return (unsigned short)r;
}

// ---------------- Kernel A: projections + 2*x outputs + bf16 Q/K to ws ----------------
__global__ __launch_bounds__(256, 4)
void proj_kernel(const float* __restrict__ x_left, const float* __restrict__ x_right,
                 const float* __restrict__ q_w, const float* __restrict__ q_b,
                 const float* __restrict__ q_gamma, const float* __restrict__ q_beta,
                 const float* __restrict__ q_mean, const float* __restrict__ q_var,
                 const float* __restrict__ k_w, const float* __restrict__ k_b,
                 const float* __restrict__ k_gamma, const float* __restrict__ k_beta,
                 const float* __restrict__ k_mean, const float* __restrict__ k_var,
                 float* __restrict__ out, unsigned short* __restrict__ ws)
{
    __shared__ float wq[CC][CC];   // [c][o] BN-folded
    __shared__ float wk[CC][CC];
    __shared__ float bq[CC], bk[CC], sq[CC], sk[CC];

    const int t    = threadIdx.x;       // pixel within row
    const int side = blockIdx.x >> 9;   // 0 = left, 1 = right
    const int bh   = blockIdx.x & 511;

    if (t < CC) {
        float qs = q_gamma[t] * rsqrtf(q_var[t] + EPSF);
        float ks = k_gamma[t] * rsqrtf(k_var[t] + EPSF);
        sq[t] = qs; sk[t] = ks;
        bq[t] = q_b[t] * qs + q_beta[t] - q_mean[t] * qs;
        bk[t] = k_b[t] * ks + k_beta[t] - k_mean[t] * ks;
    }
    __syncthreads();
    for (int r = t; r < CC * CC; r += 256) {
        int o = r >> 5, c = r & 31;
        wq[c][o] = q_w[r] * sq[o];
        wk[c][o] = k_w[r] * sk[o];
    }
    __syncthreads();

    float q[CC], k[CC];
    #pragma unroll
    for (int o = 0; o < CC; ++o) { q[o] = bq[o]; k[o] = bk[o]; }

    const float* x = side ? x_right : x_left;
    const int b = bh >> 7, h = bh & 127;
    const int xbase = (b * CC * HH + h) * WW + t;
    float* outx = out + side * O1_OFF;

    #pragma unroll 4
    for (int c = 0; c < CC; ++c) {
        int idx = xbase + c * (HH * WW);
        float xv = x[idx];
        outx[idx] = 2.0f * xv;
        #pragma unroll
        for (int o = 0; o < CC; ++o) {
            q[o] += xv * wq[c][o];
            k[o] += xv * wk[c][o];
        }
    }

    unsigned short* qdst = ws + WS_Q(side) + (bh * WW + t) * CC;
    unsigned short* kdst = ws + WS_K(side) + (bh * WW + t) * CC;
    #pragma unroll
    for (int g = 0; g < 4; ++g) {
        uint4 vq, vk;
        vq.x = f2bf(q[8*g+0]) | ((unsigned)f2bf(q[8*g+1]) << 16);
        vq.y = f2bf(q[8*g+2]) | ((unsigned)f2bf(q[8*g+3]) << 16);
        vq.z = f2bf(q[8*g+4]) | ((unsigned)f2bf(q[8*g+5]) << 16);
        vq.w = f2bf(q[8*g+6]) | ((unsigned)f2bf(q[8*g+7]) << 16);
        vk.x = f2bf(k[8*g+0]) | ((unsigned)f2bf(k[8*g+1]) << 16);
        vk.y = f2bf(k[8*g+2]) | ((unsigned)f2bf(k[8*g+3]) << 16);
        vk.z = f2bf(k[8*g+4]) | ((unsigned)f2bf(k[8*g+5]) << 16);
        vk.w = f2bf(k[8*g+6]) | ((unsigned)f2bf(k[8*g+7]) << 16);
        ((uint4*)qdst)[g] = vq;
        ((uint4*)kdst)[g] = vk;
    }
}

// ---------------- Kernel B: MFMA scores + cost stream ----------------
// block = one (dir, bh, 32-row tile). LDS: phase1 Q[32][32]+K[128][32] bf16 (10 KB),
// phase2 reuses same memory as Sbuf[32][132] fp32 (16.9 KB).
__global__ __launch_bounds__(256, 6)
void score_kernel(const float* __restrict__ cost, const unsigned short* __restrict__ ws,
                  float* __restrict__ out)
{
    __shared__ char lds[32 * 132 * 4];
    unsigned short* Qs = (unsigned short*)lds;          // [32][32]
    unsigned short* Ks = (unsigned short*)(lds + 2048); // [128][32]
    float* Sb = (float*)lds;                            // [32][132]

    const int t    = threadIdx.x;
    const int bx   = blockIdx.x;
    const int tile = bx & 7;
    const int bh   = (bx >> 3) & 511;
    const int dir  = bx >> 12;
    const int i0   = tile * 32;
    const int wbase = dir ? i0 : (i0 - 96);

    // dir0 (r2l): Q from left, K from right; dir1 (l2r): Q from right, K from left
    const unsigned short* qsrc = ws + (dir ? WS_Q(1) : WS_Q(0)) + bh * WW * CC;
    const unsigned short* ksrc = ws + (dir ? WS_K(0) : WS_K(1)) + bh * WW * CC;

    // stage Q: rows [i0, i0+32), 2 KB
    if (t < 128) {
        ((uint4*)Qs)[t] = ((const uint4*)(qsrc + i0 * CC))[t];
    }
    // stage K: cols [wbase, wbase+128), zero-fill OOB, 8 KB = 512 uint4
    {
        uint4* dst = (uint4*)Ks;
        #pragma unroll
        for (int qq = t; qq < 512; qq += 256) {
            int col = wbase + (qq >> 2);
            uint4 v = make_uint4(0u, 0u, 0u, 0u);
            if (col >= 0 && col < WW)
                v = ((const uint4*)(ksrc + col * CC))[qq & 3];
            dst[qq] = v;
        }
    }
    __syncthreads();

    // MFMA: wave w -> window cols [32w, 32w+32) (2 n-tiles) x 2 m-tiles (rows)
    const int w = t >> 6, lane = t & 63;
    const int quad = lane >> 4, l16 = lane & 15;
    f32x4 acc[2][2] = {};
    bf16x8 afrag[2], bfrag[2];
    #pragma unroll
    for (int mt = 0; mt < 2; ++mt)
        afrag[mt] = *(const bf16x8*)(Qs + (16 * mt + l16) * CC + quad * 8);
    #pragma unroll
    for (int nt = 0; nt < 2; ++nt)
        bfrag[nt] = *(const bf16x8*)(Ks + (32 * w + 16 * nt + l16) * CC + quad * 8);
    #pragma unroll
    for (int mt = 0; mt < 2; ++mt)
        #pragma unroll
        for (int nt = 0; nt < 2; ++nt)
            acc[mt][nt] = __builtin_amdgcn_mfma_f32_16x16x32_bf16(
                afrag[mt], bfrag[nt], acc[mt][nt], 0, 0, 0);
    __syncthreads();   // all K/Q LDS reads done before Sbuf overwrite

    #pragma unroll
    for (int mt = 0; mt < 2; ++mt)
        #pragma unroll
        for (int nt = 0; nt < 2; ++nt) {
            int cl = 32 * w + 16 * nt + l16;
            #pragma unroll
            for (int r = 0; r < 4; ++r) {
                int row = 16 * mt + quad * 4 + r;
                Sb[row * 132 + cl] = acc[mt][nt][r];
            }
        }
    __syncthreads();

    // stream full 32x256 cost tile, float4/lane, 8 loads batched in flight
    const float* csrc = cost + (size_t)dir * COST1 + (size_t)bh * (WW * WW);
    float* odst = out + O2_OFF + (size_t)dir * COST1 + (size_t)bh * (WW * WW);
    const int rowlane = t >> 6;        // 0..3
    const int c4 = 4 * (t & 63);
    const float inv32 = 1.0f / 32.0f;

    float4 vbuf[8];
    #pragma unroll
    for (int p = 0; p < 8; ++p) {
        int rl = 4 * p + rowlane;
        vbuf[p] = *(const float4*)(csrc + (i0 + rl) * WW + c4);
    }
    #pragma unroll
    for (int p = 0; p < 8; ++p) {
        int rl = 4 * p + rowlane;
        int i = i0 + rl;
        float4 v = vbuf[p];
        int lc = c4 - wbase;
        if (lc >= 0 && lc < 128) {
            const float4 s = *(const float4*)(Sb + rl * 132 + lc);
            int d0 = dir ? (c4 + 0 - i) : (i - c4 - 0);
            int d1 = dir ? (c4 + 1 - i) : (i - c4 - 1);
            int d2 = dir ? (c4 + 2 - i) : (i - c4 - 2);
            int d3 = dir ? (c4 + 3 - i) : (i - c4 - 3);
            if (d0 >= 0 && d0 < CR) v.x += s.x * inv32;
            if (d1 >= 0 && d1 < CR) v.y += s.y * inv32;
            if (d2 >= 0 && d2 < CR) v.z += s.z * inv32;
            if (d3 >= 0 && d3 < CR) v.w += s.w * inv32;
        }
        *(float4*)(odst + i * WW + c4) = v;
    }
}

// ---------------- Fallback (R1 kernel) if ws too small ----------------
__global__ __launch_bounds__(256, 2)
void pab_fused(const float* __restrict__ x_left, const float* __restrict__ x_right,
               const float* __restrict__ cost,
               const float* __restrict__ q_w, const float* __restrict__ q_b,
               const float* __restrict__ q_gamma, const float* __restrict__ q_beta,
               const float* __restrict__ q_mean, const float* __restrict__ q_var,
               const float* __restrict__ k_w, const float* __restrict__ k_b,
               const float* __restrict__ k_gamma, const float* __restrict__ k_beta,
               const float* __restrict__ k_mean, const float* __restrict__ k_var,
               float* __restrict__ out)
{
    __shared__ float qwt[CC][CC];
    __shared__ float kwt[CC][CC];
    __shared__ float qbf[CC], kbf[CC], qsc[CC], ksc[CC];
    __shared__ float Qls[WW][CC];
    __shared__ float Qrs[WW][CC];

    const int t   = threadIdx.x;
    const int bid = blockIdx.x;
    const int b   = bid >> 7;
    const int h   = bid & 127;

    if (t < CC) {
        float qs = q_gamma[t] * rsqrtf(q_var[t] + EPSF);
        float ks = k_gamma[t] * rsqrtf(k_var[t] + EPSF);
        qsc[t] = qs; ksc[t] = ks;
        qbf[t] = q_b[t] * qs + q_beta[t] - q_mean[t] * qs;
        kbf[t] = k_b[t] * ks + k_beta[t] - k_mean[t] * ks;
    }
    __syncthreads();
    for (int r = t; r < CC * CC; r += 256) {
        int o = r >> 5, c = r & 31;
        qwt[c][o] = q_w[r] * qsc[o];
        kwt[c][o] = k_w[r] * ksc[o];
    }
    __syncthreads();

    float ql[CC], qr[CC], kl[CC], kr[CC];
    #pragma unroll
    for (int o = 0; o < CC; ++o) {
        float qb0 = qbf[o], kb0 = kbf[o];
        ql[o] = qb0; qr[o] = qb0; kl[o] = kb0; kr[o] = kb0;
    }
    const int xbase = (b * CC * HH + h) * WW + t;
    #pragma unroll 4
    for (int c = 0; c < CC; ++c) {
        int idx = xbase + c * (HH * WW);
        float xl = x_left[idx];
        float xr = x_right[idx];
        out[idx]          = 2.0f * xl;
        out[O1_OFF + idx] = 2.0f * xr;
        #pragma unroll
        for (int o = 0; o < CC; ++o) {
            float qw = qwt[c][o];
            float kw = kwt[c][o];
            ql[o] += xl * qw;
            kl[o] += xl * kw;
            qr[o] += xr * qw;
            kr[o] += xr * kw;
        }
    }
    #pragma unroll
    for (int o = 0; o < CC; o += 4) {
        *(float4*)&Qls[t][o] = make_float4(ql[o], ql[o+1], ql[o+2], ql[o+3]);
        *(float4*)&Qrs[t][o] = make_float4(qr[o], qr[o+1], qr[o+2], qr[o+3]);
    }
    __syncthreads();

    const int rowbase = bid * (WW * WW) + t;
    const float* __restrict__ c0 = cost + rowbase;
    const float* __restrict__ c1 = cost + COST1 + rowbase;
    float* __restrict__ o2 = out + O2_OFF + rowbase;
    float* __restrict__ o3 = out + O2_OFF + COST1 + rowbase;

    #pragma unroll 2
    for (int i = 0; i < WW; ++i) {
        float v0 = c0[i * WW];
        float v1 = c1[i * WW];
        int d = i - t;
        if (d >= 0 && d < CR) {
            float s = 0.f;
            #pragma unroll
            for (int o = 0; o < CC; o += 4) {
                float4 q = *(const float4*)&Qls[i][o];
                s += q.x * kr[o] + q.y * kr[o+1] + q.z * kr[o+2] + q.w * kr[o+3];
            }
            v0 += s * (1.0f / 32.0f);
        }
        if (d <= 0 && d > -CR) {
            float s = 0.f;
            #pragma unroll
            for (int o = 0; o < CC; o += 4) {
                float4 q = *(const float4*)&Qrs[i][o];
                s += q.x * kl[o] + q.y * kl[o+1] + q.z * kl[o+2] + q.w * kl[o+3];
            }
            v1 += s * (1.0f / 32.0f);
        }
        o2[i * WW] = v0;
        o3[i * WW] = v1;
    }
}

extern "C" void kernel_launch(void* const* d_in, const int* in_sizes, int n_in,
                              void* d_out, int out_size, void* d_ws, size_t ws_size,
                              hipStream_t stream) {
    const float* x_left  = (const float*)d_in[0];
    const float* x_right = (const float*)d_in[1];
    const float* cost    = (const float*)d_in[2];
    const float* q_w     = (const float*)d_in[3];
    const float* q_b     = (const float*)d_in[4];
    const float* q_gamma = (const float*)d_in[5];
    const float* q_beta  = (const float*)d_in[6];
    const float* q_mean  = (const float*)d_in[7];
    const float* q_var   = (const float*)d_in[8];
    const float* k_w     = (const float*)d_in[9];
    const float* k_b     = (const float*)d_in[10];
    const float* k_gamma = (const float*)d_in[11];
    const float* k_beta  = (const float*)d_in[12];
    const float* k_mean  = (const float*)d_in[13];
    const float* k_var   = (const float*)d_in[14];
    float* out = (float*)d_out;

    if (ws_size >= WS_NEEDED) {
        unsigned short* ws = (unsigned short*)d_ws;
        proj_kernel<<<dim3(1024), dim3(256), 0, stream>>>(
            x_left, x_right,
            q_w, q_b, q_gamma, q_beta, q_mean, q_var,
            k_w, k_b, k_gamma, k_beta, k_mean, k_var,
            out, ws);
        score_kernel<<<dim3(8192), dim3(256), 0, stream>>>(cost, ws, out);
    } else {
        pab_fused<<<dim3(BB * HH), dim3(256), 0, stream>>>(
            x_left, x_right, cost,
            q_w, q_b, q_gamma, q_beta, q_mean, q_var,
            k_w, k_b, k_gamma, k_beta, k_mean, k_var,
            out);
    }
}